// Round 1
// baseline (105.793 us; speedup 1.0000x reference)
//
#include <hip/hip_runtime.h>
#include <math.h>

#define KK 32
#define CC 256

// ---------------------------------------------------------------------------
// Kernel 1: grid 320.
//  blocks 0..255  : per-(b,m) stats (UNCHANGED arithmetic: stage x in LDS,
//                   row means, center, cov upper-tri 2x2 tiles with BIT-EXACT
//                   sequential fma chain — adj>0 mask is knife-edge), adj out,
//                   means -> mean_ws.  cov loop now unrolled x4 (latency).
//  blocks 256..319: A rows from W1 (bit-identical reduction order to mlp1:
//                   A[o,k] = 0.5f*rowsum_k + colsum_k - 0.5f*W1[o,33k]),
//                   8 rows per block, hidden under the stats blocks.
// ---------------------------------------------------------------------------
union PrepSMem {
    struct {
        float xs[KK][258];
        float covm[KK][KK + 1];
        float part8[256];
        float meanv[KK];
        float stdv[KK];
    } p;
    float rowlds[8][1056];   // 33,792 B  <= 38,528 B of .p
};

__global__ __launch_bounds__(256) void prep_kernel(
    const float* __restrict__ x, const float* __restrict__ W1,
    float* __restrict__ mean_ws, float* __restrict__ A_ws,
    float* __restrict__ adj_out)
{
    __shared__ PrepSMem sm;
    const int t = threadIdx.x;

    if (blockIdx.x >= 256) {
        // ---------------- A-compute branch (64 blocks x 8 rows) ------------
        const int ab = blockIdx.x - 256;            // 0..63
        const float* wr = W1 + (size_t)ab * 8 * 1024;
        #pragma unroll
        for (int u = 0; u < 8; ++u) {
            const int e4 = t + u * 256;             // float4 idx over 8 rows
            const int q  = e4 >> 8;                 // row 0..7
            const int e  = (e4 & 255) * 4;          // elem 0..1023
            const float4 v = *(const float4*)(wr + q * 1024 + e);
            const int f = (e >> 5) * 33 + (e & 31); // same transform as mlp1
            sm.rowlds[q][f] = v.x; sm.rowlds[q][f + 1] = v.y;
            sm.rowlds[q][f + 2] = v.z; sm.rowlds[q][f + 3] = v.w;
        }
        __syncthreads();
        {
            const int k = t & 31, q = t >> 5;       // 8 rows x 32 k = 256
            float rs = 0.f, cs = 0.f;
            #pragma unroll
            for (int j = 0; j < 32; ++j) rs += sm.rowlds[q][k * 33 + j];
            #pragma unroll
            for (int i = 0; i < 32; ++i) cs += sm.rowlds[q][i * 33 + k];
            A_ws[(size_t)(ab * 8 + q) * 32 + k] =
                0.5f * rs + cs - 0.5f * sm.rowlds[q][k * 34];
        }
        return;
    }

    // -------------------- stats branch (blocks 0..255) ---------------------
    const int bm = blockIdx.x;            // 0..255
    const int b  = bm >> 6, m = bm & 63;
    const float* xp = x + (size_t)bm * (KK * CC);

    #pragma unroll
    for (int s = 0; s < 8; ++s) {
        const int e = s * 1024 + t * 4;
        const float4 v = *(const float4*)(xp + e);
        const int i = e >> 8, col = e & 255;
        sm.p.xs[i][col] = v.x; sm.p.xs[i][col + 1] = v.y;
        sm.p.xs[i][col + 2] = v.z; sm.p.xs[i][col + 3] = v.w;
    }
    __syncthreads();
    {
        const int i = t >> 3, part = t & 7;
        float s = 0.f;
        const int c0 = part * 32;
        #pragma unroll
        for (int c = 0; c < 32; ++c) s += sm.p.xs[i][c0 + c];
        sm.p.part8[t] = s;
    }
    __syncthreads();
    if (t < KK) {
        float s = 0.f;
        #pragma unroll
        for (int k = 0; k < 8; ++k) s += sm.p.part8[t * 8 + k];
        sm.p.meanv[t] = s * (1.0f / CC);
        mean_ws[(size_t)(b * 32 + t) * 64 + m] = sm.p.meanv[t];
    }
    __syncthreads();
    {
        const int r = t >> 3, c0 = (t & 7) * 32;
        const float mv = sm.p.meanv[r];
        #pragma unroll
        for (int c = 0; c < 32; ++c) sm.p.xs[r][c0 + c] -= mv;
    }
    __syncthreads();
    if (t < 136) {
        int rem = t, r = 0;
        while (rem >= 16 - r) { rem -= 16 - r; ++r; }
        const int ti = r, tj = r + rem;
        const int i0 = 2 * ti, i1 = i0 + 1, j0 = 2 * tj, j1 = j0 + 1;
        float c00 = 0.f, c01 = 0.f, c10 = 0.f, c11 = 0.f;
        #pragma unroll 4
        for (int c = 0; c < CC; c += 2) {
            const float2 a0 = *(const float2*)&sm.p.xs[i0][c];
            const float2 a1 = *(const float2*)&sm.p.xs[i1][c];
            const float2 b0 = *(const float2*)&sm.p.xs[j0][c];
            const float2 b1 = *(const float2*)&sm.p.xs[j1][c];
            // sequential fma chain per accumulator — bit-exact
            c00 += a0.x * b0.x; c00 += a0.y * b0.y;
            c01 += a0.x * b1.x; c01 += a0.y * b1.y;
            c10 += a1.x * b0.x; c10 += a1.y * b0.y;
            c11 += a1.x * b1.x; c11 += a1.y * b1.y;
        }
        c00 *= (1.0f / (CC - 1)); c01 *= (1.0f / (CC - 1));
        c10 *= (1.0f / (CC - 1)); c11 *= (1.0f / (CC - 1));
        sm.p.covm[i0][j0] = c00; sm.p.covm[i0][j1] = c01;
        sm.p.covm[i1][j0] = c10; sm.p.covm[i1][j1] = c11;
        sm.p.covm[j0][i0] = c00; sm.p.covm[j1][i0] = c01;
        sm.p.covm[j0][i1] = c10; sm.p.covm[j1][i1] = c11;
    }
    __syncthreads();
    if (t < KK) sm.p.stdv[t] = sqrtf(sm.p.covm[t][t]);
    __syncthreads();
    #pragma unroll
    for (int k = 0; k < 4; ++k) {
        const int pair = t + k * 256;
        const int i = pair >> 5, j = pair & 31;
        adj_out[(size_t)bm * 1024 + pair] =
            sm.p.covm[i][j] / (sm.p.stdv[i] * sm.p.stdv[j]);
    }
}

// ---------------------------------------------------------------------------
// Kernel 2 (tiny): h = gelu(A @ mean) per (b,m). 256 blocks x 256 threads,
// thread t computes o = 2t, 2t+1.  Chain k-ascending — bit-exact vs mlp1.
// NEW h layout: h_ws[b][m][c]  (contiguous per (b,m) row -> float4 loads in
// the e-kernel).
// ---------------------------------------------------------------------------
__global__ __launch_bounds__(256) void h_kernel(
    const float* __restrict__ A_ws, const float* __restrict__ mean_ws,
    float* __restrict__ h_ws)
{
    __shared__ float meanv[KK];
    const int t  = threadIdx.x;
    const int bm = blockIdx.x;
    const int b  = bm >> 6, m = bm & 63;
    if (t < KK) meanv[t] = mean_ws[(size_t)(b * 32 + t) * 64 + m];
    __syncthreads();

    const int o0 = t * 2;
    const float* a0 = A_ws + (size_t)o0 * 32;
    const float* a1 = a0 + 32;
    float r0[32], r1[32];
    #pragma unroll
    for (int u = 0; u < 8; ++u) {
        *(float4*)&r0[u * 4] = *(const float4*)(a0 + u * 4);
        *(float4*)&r1[u * 4] = *(const float4*)(a1 + u * 4);
    }
    float s0 = 0.f, s1 = 0.f;
    #pragma unroll
    for (int k = 0; k < 32; ++k) {
        s0 += r0[k] * meanv[k];    // k-ascending, bit-exact
        s1 += r1[k] * meanv[k];
    }
    const float g0 = 0.5f * s0 * (1.0f + erff(s0 * 0.70710678118654752f));
    const float g1 = 0.5f * s1 * (1.0f + erff(s1 * 0.70710678118654752f));
    float2 st; st.x = g0; st.y = g1;
    *(float2*)&h_ws[(size_t)(b * 64 + m) * 512 + o0] = st;
}

// ---------------------------------------------------------------------------
// Kernel 3: e = sigmoid(W2 @ h). Block = 16 o x 64 m (4 waves), grid (64,4).
// W2 tile in LDS, wave-uniform float4 broadcasts. h now [b][m][c]: each
// thread loads its own row as float4 (128 loads vs 2048 scalars). Acc chain
// c-ascending, same fmac sequence — bit-exact.  e_ws layout [b][m][o].
// ---------------------------------------------------------------------------
__global__ __launch_bounds__(256) void e_kernel(
    const float* __restrict__ W2, const float* __restrict__ h_ws,
    float* __restrict__ e_ws)
{
    __shared__ float W2s[16][512];     // 32 KB
    const int m  = threadIdx.x;        // 0..63
    const int ow = threadIdx.y;        // 0..3
    const int b  = blockIdx.y;
    const int ob = blockIdx.x * 16;

    {
        const int t = ow * 64 + m;
        const float* src = W2 + (size_t)ob * 512;
        #pragma unroll
        for (int u = 0; u < 8; ++u) {
            const int e4 = t + u * 256;
            const float4 v = *(const float4*)(src + e4 * 4);
            *(float4*)&W2s[e4 >> 7][(e4 & 127) * 4] = v;
        }
    }
    __syncthreads();

    const float* hb = h_ws + (size_t)(b * 64 + m) * 512;
    float acc[4] = {0.f, 0.f, 0.f, 0.f};
    const int ol = ow * 4;

    #pragma unroll 4
    for (int c = 0; c < 512; c += 4) {
        const float4 hv = *(const float4*)(hb + c);
        #pragma unroll
        for (int q = 0; q < 4; ++q) {
            const float4 w = *(const float4*)&W2s[ol + q][c];  // broadcast
            acc[q] += w.x * hv.x;
            acc[q] += w.y * hv.y;
            acc[q] += w.z * hv.z;
            acc[q] += w.w * hv.w;
        }
    }
    float4 sv;
    sv.x = 1.0f / (1.0f + expf(-acc[0]));
    sv.y = 1.0f / (1.0f + expf(-acc[1]));
    sv.z = 1.0f / (1.0f + expf(-acc[2]));
    sv.w = 1.0f / (1.0f + expf(-acc[3]));
    *(float4*)&e_ws[(size_t)(b * 64 + m) * 1024 + ob + ol] = sv;
}

// ---------------------------------------------------------------------------
// Kernel 4: masked softmax (mask adj>0) + att @ x.  256 blocks (b,m).
// Unchanged arithmetic; PV loop unrolled x2 (latency).
// ---------------------------------------------------------------------------
__global__ __launch_bounds__(256) void softmax_out_kernel(
    const float* __restrict__ x, const float* __restrict__ e_ws,
    const float* __restrict__ adj, float* __restrict__ out)
{
    __shared__ float xs[KK][260];
    __shared__ float att[KK][KK + 1];
    const int bm = blockIdx.x;
    const int b  = bm >> 6, m = bm & 63;
    const int t  = threadIdx.x;
    const float* xp = x + (size_t)bm * (KK * CC);

    #pragma unroll
    for (int s = 0; s < 8; ++s) {
        const int e = s * 1024 + t * 4;
        const float4 v = *(const float4*)(xp + e);
        *(float4*)&xs[e >> 8][e & 255] = v;
    }
    {
        const int p0 = 4 * t;
        const float4 ev4 = *(const float4*)&e_ws[(size_t)(b * 64 + m) * 1024 + p0];
        const float4 aj4 = *(const float4*)&adj[(size_t)bm * 1024 + p0];
        const int i = p0 >> 5, j0 = p0 & 31;
        att[i][j0]     = (aj4.x > 0.f) ? ev4.x : -INFINITY;
        att[i][j0 + 1] = (aj4.y > 0.f) ? ev4.y : -INFINITY;
        att[i][j0 + 2] = (aj4.z > 0.f) ? ev4.z : -INFINITY;
        att[i][j0 + 3] = (aj4.w > 0.f) ? ev4.w : -INFINITY;
    }
    __syncthreads();
    if (t < KK) {
        float mx = -INFINITY;
        #pragma unroll
        for (int j = 0; j < KK; ++j) mx = fmaxf(mx, att[t][j]);
        float s = 0.f;
        #pragma unroll
        for (int j = 0; j < KK; ++j) {
            const float v = expf(att[t][j] - mx);
            att[t][j] = v;
            s += v;
        }
        const float inv = 1.0f / s;
        #pragma unroll
        for (int j = 0; j < KK; ++j) att[t][j] *= inv;
    }
    __syncthreads();

    const int c8 = t & 31, iq = t >> 5;
    const int i0 = iq * 4;
    const int cA = 4 * c8, cB = 128 + 4 * c8;
    float4 accA[4], accB[4];
    #pragma unroll
    for (int r = 0; r < 4; ++r) {
        accA[r] = make_float4(0.f, 0.f, 0.f, 0.f);
        accB[r] = make_float4(0.f, 0.f, 0.f, 0.f);
    }
    #pragma unroll 2
    for (int j = 0; j < KK; ++j) {
        const float4 xa = *(const float4*)&xs[j][cA];
        const float4 xb = *(const float4*)&xs[j][cB];
        #pragma unroll
        for (int r = 0; r < 4; ++r) {
            const float av = att[i0 + r][j];
            accA[r].x += av * xa.x; accA[r].y += av * xa.y;
            accA[r].z += av * xa.z; accA[r].w += av * xa.w;
            accB[r].x += av * xb.x; accB[r].y += av * xb.y;
            accB[r].z += av * xb.z; accB[r].w += av * xb.w;
        }
    }
    float* op = out + (size_t)bm * (KK * CC);
    #pragma unroll
    for (int r = 0; r < 4; ++r) {
        *(float4*)(op + (size_t)(i0 + r) * CC + cA) = accA[r];
        *(float4*)(op + (size_t)(i0 + r) * CC + cB) = accB[r];
    }
}

extern "C" void kernel_launch(void* const* d_in, const int* in_sizes, int n_in,
                              void* d_out, int out_size, void* d_ws, size_t ws_size,
                              hipStream_t stream) {
    const float* x  = (const float*)d_in[0];   // (4,64,32,256)
    const float* W1 = (const float*)d_in[1];   // (512,1024)
    const float* W2 = (const float*)d_in[2];   // (1024,512)
    float* out     = (float*)d_out;                       // 2,097,152 floats
    float* adj_out = out + (size_t)4 * 64 * 32 * 256;     // +262,144 floats

    float* mean_ws = (float*)d_ws;                    // 4*32*64   =   8,192
    float* A_ws    = mean_ws + 8192;                  // 512*32    =  16,384
    float* h_ws    = A_ws + 16384;                    // 4*64*512  = 131,072
    float* e_ws    = h_ws + 131072;                   // 4*64*1024 = 262,144

    prep_kernel<<<320, 256, 0, stream>>>(x, W1, mean_ws, A_ws, adj_out);
    h_kernel<<<256, 256, 0, stream>>>(A_ws, mean_ws, h_ws);
    e_kernel<<<dim3(64, 4), dim3(64, 4), 0, stream>>>(W2, h_ws, e_ws);
    softmax_out_kernel<<<256, 256, 0, stream>>>(x, e_ws, adj_out, out);
}